// Round 6
// baseline (746.259 us; speedup 1.0000x reference)
//
#include <hip/hip_runtime.h>
#include <cstdint>
#include <cstddef>

// Problem constants (from reference)
constexpr int N_NODES = 100000;
constexpr int N_EDGES = 1000000;
constexpr int HC = 64;   // total channels per layer (H*C) — 64 for both layers
constexpr int ED = 32;   // edge feature dim

// ============================ CSR build ============================
__global__ void zero_int(int* __restrict__ p, int n) {
    int i = blockIdx.x * blockDim.x + threadIdx.x;
    if (i < n) p[i] = 0;
}

__global__ void hist_kernel(const int* __restrict__ dst, int* __restrict__ cnt) {
    int i = blockIdx.x * blockDim.x + threadIdx.x;
    if (i < N_EDGES) atomicAdd(&cnt[dst[i]], 1);
}

// per-block (1024 elems) exclusive scan + block sums
__global__ __launch_bounds__(256) void scan1(const int* __restrict__ cnt,
    int* __restrict__ excl, int* __restrict__ bsum, int n) {
    __shared__ int sh[256];
    int b = blockIdx.x, t = threadIdx.x;
    int base = b * 1024 + t * 4;
    int v0 = (base + 0 < n) ? cnt[base + 0] : 0;
    int v1 = (base + 1 < n) ? cnt[base + 1] : 0;
    int v2 = (base + 2 < n) ? cnt[base + 2] : 0;
    int v3 = (base + 3 < n) ? cnt[base + 3] : 0;
    int s = v0 + v1 + v2 + v3;
    sh[t] = s;
    __syncthreads();
    for (int off = 1; off < 256; off <<= 1) {
        int val = (t >= off) ? sh[t - off] : 0;
        __syncthreads();
        sh[t] += val;
        __syncthreads();
    }
    int prefix = sh[t] - s;
    if (t == 255) bsum[b] = sh[255];
    if (base + 0 < n) excl[base + 0] = prefix;
    if (base + 1 < n) excl[base + 1] = prefix + v0;
    if (base + 2 < n) excl[base + 2] = prefix + v0 + v1;
    if (base + 3 < n) excl[base + 3] = prefix + v0 + v1 + v2;
}

// single-block exclusive scan of block sums (nb <= 128)
__global__ __launch_bounds__(128) void scan2(int* __restrict__ bsum, int nb) {
    __shared__ int sh[128];
    int t = threadIdx.x;
    int v = (t < nb) ? bsum[t] : 0;
    sh[t] = v;
    __syncthreads();
    for (int off = 1; off < 128; off <<= 1) {
        int val = (t >= off) ? sh[t - off] : 0;
        __syncthreads();
        sh[t] += val;
        __syncthreads();
    }
    if (t < nb) bsum[t] = sh[t] - v;
}

__global__ void scan3(const int* __restrict__ excl, const int* __restrict__ bsum,
                      int* __restrict__ rowptr, int* __restrict__ cursor, int n) {
    int i = blockIdx.x * blockDim.x + threadIdx.x;
    if (i < n) { int r = excl[i] + bsum[i >> 10]; rowptr[i] = r; cursor[i] = r; }
    if (i == n) rowptr[n] = N_EDGES;
}

// scatter edge id AND its src node into dst-sorted order
__global__ void scatter_kernel(const int* __restrict__ dst, const int* __restrict__ src,
                               int* __restrict__ cursor,
                               int* __restrict__ perm, int* __restrict__ srcs) {
    int e = blockIdx.x * blockDim.x + threadIdx.x;
    if (e < N_EDGES) {
        int p = atomicAdd(&cursor[dst[e]], 1);
        perm[p] = e;
        srcs[p] = src[e];
    }
}

// ============================ node GEMM ============================
// o = x@W + b, four weight sets selected by block; k/v interleave into kv[N][128].
template<int K>
__global__ __launch_bounds__(256) void node_gemm(
    const float* __restrict__ x,
    const float* __restrict__ Wq, const float* __restrict__ bq,
    const float* __restrict__ Wk, const float* __restrict__ bk,
    const float* __restrict__ Wv, const float* __restrict__ bv,
    const float* __restrict__ Ws, const float* __restrict__ bs,
    float* __restrict__ q, float* __restrict__ kv,
    float* __restrict__ sk, int N)
{
    __shared__ float As[32][64];   // x tile, transposed: As[k][m]
    __shared__ float Bs[32][64];   // W tile: Bs[k][n]

    int bid = blockIdx.x;
    int mt  = bid >> 2;
    int mat = bid & 3;
    const float* W; const float* b; float* o; int ldo;
    switch (mat) {
        case 0:  W = Wq; b = bq; o = q;       ldo = 64;  break;
        case 1:  W = Wk; b = bk; o = kv;      ldo = 128; break;
        case 2:  W = Wv; b = bv; o = kv + 64; ldo = 128; break;
        default: W = Ws; b = bs; o = sk;      ldo = 64;  break;
    }

    int t = threadIdx.x;
    int m0 = mt * 64;
    int tx = t & 15, ty = t >> 4;
    int mload = t & 63;
    int kq0   = t >> 6;
    int row   = min(m0 + mload, N - 1);

    float acc[4][4] = {};

    for (int k0 = 0; k0 < K; k0 += 32) {
        #pragma unroll
        for (int i = 0; i < 2; ++i) {
            int kq = kq0 + 4 * i;
            float4 xv = *(const float4*)&x[(size_t)row * K + k0 + kq * 4];
            #pragma unroll
            for (int c = 0; c < 4; ++c) As[kq * 4 + c][mload] = ((const float*)&xv)[c];
        }
        #pragma unroll
        for (int i = 0; i < 2; ++i) {
            int kr = ty + 16 * i;
            *(float4*)&Bs[kr][tx * 4] = *(const float4*)&W[(size_t)(k0 + kr) * 64 + tx * 4];
        }
        __syncthreads();
        #pragma unroll
        for (int kk = 0; kk < 32; ++kk) {
            float4 a  = *(const float4*)&As[kk][ty * 4];
            float4 bb = *(const float4*)&Bs[kk][tx * 4];
            #pragma unroll
            for (int i = 0; i < 4; ++i)
                #pragma unroll
                for (int j = 0; j < 4; ++j)
                    acc[i][j] = fmaf(((const float*)&a)[i], ((const float*)&bb)[j], acc[i][j]);
        }
        __syncthreads();
    }

    float4 bias = *(const float4*)&b[tx * 4];
    #pragma unroll
    for (int i = 0; i < 4; ++i) {
        int m = m0 + ty * 4 + i;
        if (m < N) {
            float4 r;
            #pragma unroll
            for (int j = 0; j < 4; ++j) ((float*)&r)[j] = acc[i][j] + ((const float*)&bias)[j];
            *(float4*)&o[(size_t)m * ldo + tx * 4] = r;
        }
    }
}

// ============================ CSR edge pass v2 ============================
// One wave per destination node; 16-edge chunks; all chunk metadata and ef rows
// batch-loaded (coalesced, independent); kv gathers prefetched 1 edge ahead;
// ee inner product reads ef from LDS as uniform-address float4 broadcasts.
template<int C, int CHUNK>
__global__ __launch_bounds__(256) void edge_csr(
    const int* __restrict__ rowptr, const int* __restrict__ perm,
    const int* __restrict__ srcs, const float* __restrict__ ef,
    const float* __restrict__ We, const float* __restrict__ q,
    const float* __restrict__ kv, const float* __restrict__ sk,
    float* __restrict__ out, float scale, int do_relu)
{
    __shared__ float efs[4][CHUNK][32];     // per-wave ef staging
    int lane  = threadIdx.x & 63;
    int wslot = threadIdx.x >> 6;
    int half  = lane >> 5;                  // 0/1: which ef row of a pair
    int col   = lane & 31;

    float we[ED];                           // We column for this lane (VGPRs)
    #pragma unroll
    for (int j = 0; j < ED; ++j) we[j] = We[j * HC + lane];

    int wid = blockIdx.x * 4 + wslot;
    int nw  = gridDim.x * 4;

    for (int d0 = wid; d0 < N_NODES; d0 += nw) {
        int d = __builtin_amdgcn_readfirstlane(d0);
        int r0 = rowptr[d], r1 = rowptr[d + 1];
        float qv = q[(size_t)d * HC + lane];
        float racc = 0.f, rden = 0.f;

        for (int c0 = r0; c0 < r1; c0 += CHUNK) {
            int rem = min(CHUNK, r1 - c0);

            // chunk metadata: coalesced lane-parallel loads
            int e_l = (lane < rem) ? perm[c0 + lane] : 0;
            int s_l = (lane < rem) ? srcs[c0 + lane] : 0;

            // stage ef rows, 2 rows per unrolled iteration (independent loads)
            #pragma unroll
            for (int i = 0; i < CHUNK; i += 2) {
                int r = i + half;
                int e_r = __shfl(e_l, min(r, rem - 1), 64);
                if (r < rem) efs[wslot][r][col] = ef[(size_t)e_r * ED + col];
            }

            // kv prefetch for edge 0
            int s_cur = __shfl(s_l, 0, 64);
            float kk_n = kv[(size_t)s_cur * 128 + lane];
            float vv_n = kv[(size_t)s_cur * 128 + 64 + lane];

            for (int i = 0; i < rem; ++i) {
                float kk = kk_n, vv = vv_n;
                if (i + 1 < rem) {          // prefetch next edge's kv
                    int s_nx = __shfl(s_l, i + 1, 64);
                    kk_n = kv[(size_t)s_nx * 128 + lane];
                    vv_n = kv[(size_t)s_nx * 128 + 64 + lane];
                }
                float ee = 0.f;
                const float* er = &efs[wslot][i][0];
                #pragma unroll
                for (int j = 0; j < ED; j += 4) {
                    float4 e4 = *(const float4*)(er + j);   // uniform addr -> broadcast
                    ee = fmaf(e4.x, we[j + 0], ee);
                    ee = fmaf(e4.y, we[j + 1], ee);
                    ee = fmaf(e4.z, we[j + 2], ee);
                    ee = fmaf(e4.w, we[j + 3], ee);
                }
                float p = qv * (kk + ee);
                #pragma unroll
                for (int off = C >> 1; off; off >>= 1) p += __shfl_xor(p, off, 64);
                float ex = __expf(p * scale);
                racc = fmaf(vv + ee, ex, racc);
                rden += ex;                 // identical across the head's C lanes
            }
        }

        float val = racc / (rden + 1e-16f) + sk[(size_t)d * HC + lane];
        if (do_relu) val = fmaxf(val, 0.f);
        out[(size_t)d * HC + lane] = val;
    }
}

extern "C" void kernel_launch(void* const* d_in, const int* in_sizes, int n_in,
                              void* d_out, int out_size, void* d_ws, size_t ws_size,
                              hipStream_t stream) {
    const float* x   = (const float*)d_in[0];
    const int*   ei  = (const int*)d_in[1];
    const float* ef  = (const float*)d_in[2];
    const float* Wq1 = (const float*)d_in[3];  const float* bq1 = (const float*)d_in[4];
    const float* Wk1 = (const float*)d_in[5];  const float* bk1 = (const float*)d_in[6];
    const float* Wv1 = (const float*)d_in[7];  const float* bv1 = (const float*)d_in[8];
    const float* We1 = (const float*)d_in[9];
    const float* Ws1 = (const float*)d_in[10]; const float* bs1 = (const float*)d_in[11];
    const float* Wq2 = (const float*)d_in[12]; const float* bq2 = (const float*)d_in[13];
    const float* Wk2 = (const float*)d_in[14]; const float* bk2 = (const float*)d_in[15];
    const float* Wv2 = (const float*)d_in[16]; const float* bv2 = (const float*)d_in[17];
    const float* We2 = (const float*)d_in[18];
    const float* Ws2 = (const float*)d_in[19]; const float* bs2 = (const float*)d_in[20];
    float* out = (float*)d_out;

    const int N = N_NODES, E = N_EDGES;
    size_t NF = (size_t)N * HC;
    float* ws = (float*)d_ws;
    float* q     = ws;                      // N*64
    float* kv    = q + NF;                  // N*128 (k | v interleaved)
    float* sk    = kv + 2 * NF;             // N*64
    float* h1    = sk + NF;                 // N*64
    int* cnt     = (int*)(h1 + NF);         // N
    int* excl    = cnt + N;                 // N
    int* bsum    = excl + N;                // 128
    int* rowptr  = bsum + 128;              // N+1
    int* cursor  = rowptr + N + 1;          // N
    int* perm    = cursor + N;              // E
    int* srcs    = perm + E;                // E

    const int* src = ei;
    const int* dst = ei + E;

    dim3 b256(256);
    int gN    = (N + 255) / 256;
    int gN1   = (N + 1 + 255) / 256;
    int gE    = (E + 255) / 256;
    int gGemm = ((N + 63) / 64) * 4;
    int gEdge = 2048;                       // 8192 persistent waves
    int nScanB = (N + 1023) / 1024;         // 98

    // ---------------- CSR build (shared by both layers) ----------------
    hipLaunchKernelGGL(zero_int, dim3(gN), b256, 0, stream, cnt, N);
    hipLaunchKernelGGL(hist_kernel, dim3(gE), b256, 0, stream, dst, cnt);
    hipLaunchKernelGGL(scan1, dim3(nScanB), b256, 0, stream, cnt, excl, bsum, N);
    hipLaunchKernelGGL(scan2, dim3(1), dim3(128), 0, stream, bsum, nScanB);
    hipLaunchKernelGGL(scan3, dim3(gN1), b256, 0, stream, excl, bsum, rowptr, cursor, N);
    hipLaunchKernelGGL(scatter_kernel, dim3(gE), b256, 0, stream, dst, src, cursor, perm, srcs);

    // ---------------- layer 1: H=2, C=32, K=128 ----------------
    hipLaunchKernelGGL((node_gemm<128>), dim3(gGemm), b256, 0, stream, x,
                       Wq1, bq1, Wk1, bk1, Wv1, bv1, Ws1, bs1, q, kv, sk, N);
    hipLaunchKernelGGL((edge_csr<32, 16>), dim3(gEdge), b256, 0, stream,
                       rowptr, perm, srcs, ef, We1, q, kv, sk, h1,
                       0.17677669529663687f, 1);

    // ---------------- layer 2: H=1, C=64, K=64 ----------------
    hipLaunchKernelGGL((node_gemm<64>), dim3(gGemm), b256, 0, stream, h1,
                       Wq2, bq2, Wk2, bk2, Wv2, bv2, Ws2, bs2, q, kv, sk, N);
    hipLaunchKernelGGL((edge_csr<64, 16>), dim3(gEdge), b256, 0, stream,
                       rowptr, perm, srcs, ef, We2, q, kv, sk, out,
                       0.125f, 0);
}

// Round 7
// 599.744 us; speedup vs baseline: 1.2443x; 1.2443x over previous
//
#include <hip/hip_runtime.h>
#include <cstdint>
#include <cstddef>

// Problem constants (from reference)
constexpr int N_NODES = 100000;
constexpr int N_EDGES = 1000000;

// ============================ CSR build ============================
__global__ void zero_int(int* __restrict__ p, int n) {
    int i = blockIdx.x * blockDim.x + threadIdx.x;
    if (i < n) p[i] = 0;
}

__global__ void hist_kernel(const int* __restrict__ dst, int* __restrict__ cnt) {
    int i = blockIdx.x * blockDim.x + threadIdx.x;
    if (i < N_EDGES) atomicAdd(&cnt[dst[i]], 1);
}

// per-block (1024 elems) exclusive scan + block sums
__global__ __launch_bounds__(256) void scan1(const int* __restrict__ cnt,
    int* __restrict__ excl, int* __restrict__ bsum, int n) {
    __shared__ int sh[256];
    int b = blockIdx.x, t = threadIdx.x;
    int base = b * 1024 + t * 4;
    int v0 = (base + 0 < n) ? cnt[base + 0] : 0;
    int v1 = (base + 1 < n) ? cnt[base + 1] : 0;
    int v2 = (base + 2 < n) ? cnt[base + 2] : 0;
    int v3 = (base + 3 < n) ? cnt[base + 3] : 0;
    int s = v0 + v1 + v2 + v3;
    sh[t] = s;
    __syncthreads();
    for (int off = 1; off < 256; off <<= 1) {
        int val = (t >= off) ? sh[t - off] : 0;
        __syncthreads();
        sh[t] += val;
        __syncthreads();
    }
    int prefix = sh[t] - s;
    if (t == 255) bsum[b] = sh[255];
    if (base + 0 < n) excl[base + 0] = prefix;
    if (base + 1 < n) excl[base + 1] = prefix + v0;
    if (base + 2 < n) excl[base + 2] = prefix + v0 + v1;
    if (base + 3 < n) excl[base + 3] = prefix + v0 + v1 + v2;
}

// single-block exclusive scan of block sums (nb <= 128)
__global__ __launch_bounds__(128) void scan2(int* __restrict__ bsum, int nb) {
    __shared__ int sh[128];
    int t = threadIdx.x;
    int v = (t < nb) ? bsum[t] : 0;
    sh[t] = v;
    __syncthreads();
    for (int off = 1; off < 128; off <<= 1) {
        int val = (t >= off) ? sh[t - off] : 0;
        __syncthreads();
        sh[t] += val;
        __syncthreads();
    }
    if (t < nb) bsum[t] = sh[t] - v;
}

__global__ void scan3(const int* __restrict__ excl, const int* __restrict__ bsum,
                      int* __restrict__ rowptr, int* __restrict__ cursor, int n) {
    int i = blockIdx.x * blockDim.x + threadIdx.x;
    if (i < n) { int r = excl[i] + bsum[i >> 10]; rowptr[i] = r; cursor[i] = r; }
    if (i == n) rowptr[n] = N_EDGES;
}

// scatter edge id AND its src node into dst-sorted order
__global__ void scatter_kernel(const int* __restrict__ dst, const int* __restrict__ src,
                               int* __restrict__ cursor,
                               int* __restrict__ perm, int* __restrict__ srcs) {
    int e = blockIdx.x * blockDim.x + threadIdx.x;
    if (e < N_EDGES) {
        int p = atomicAdd(&cursor[dst[e]], 1);
        perm[p] = e;
        srcs[p] = src[e];
    }
}

// ============================ Wg build ============================
// Wg[K,(h,j)] = sum_{c in head h} Wq[K,c]*We[j,c];  bg[(h,j)] = sum_c bq[c]*We[j,c]
// For H==1 only cols j<32 are nonzero (rest zero-padded so g is zero there).
template<int KDIM, int H>
__global__ __launch_bounds__(256) void wg_build(
    const float* __restrict__ Wq, const float* __restrict__ bq,
    const float* __restrict__ We,
    float* __restrict__ Wg, float* __restrict__ bg)
{
    __shared__ float wq[KDIM * 64];
    __shared__ float we[32 * 64];
    int t = threadIdx.x;
    for (int i = t; i < KDIM * 64; i += 256) wq[i] = Wq[i];
    for (int i = t; i < 32 * 64; i += 256) we[i] = We[i];
    __syncthreads();
    for (int idx = t; idx < KDIM * 64; idx += 256) {
        int K = idx >> 6, col = idx & 63;
        float s = 0.f;
        if (H == 2) {
            int h = col >> 5, j = col & 31;
            #pragma unroll 8
            for (int c = 0; c < 32; ++c)
                s = fmaf(wq[K * 64 + h * 32 + c], we[j * 64 + h * 32 + c], s);
        } else {
            int j = col;
            if (j < 32) {
                #pragma unroll 8
                for (int c = 0; c < 64; ++c)
                    s = fmaf(wq[K * 64 + c], we[j * 64 + c], s);
            }
        }
        Wg[idx] = s;
    }
    if (t < 64) {
        float s = 0.f;
        if (H == 2) {
            int h = t >> 5, j = t & 31;
            for (int c = 0; c < 32; ++c)
                s = fmaf(bq[h * 32 + c], we[j * 64 + h * 32 + c], s);
        } else {
            if (t < 32)
                for (int c = 0; c < 64; ++c)
                    s = fmaf(bq[c], we[t * 64 + c], s);
        }
        bg[t] = s;
    }
}

// ============================ node GEMM ============================
// o = x@W + b, FIVE weight sets selected by block (q, k, v, skip, g);
// k/v interleave into kv[N][128].
template<int K>
__global__ __launch_bounds__(256) void node_gemm(
    const float* __restrict__ x,
    const float* __restrict__ Wq, const float* __restrict__ bq,
    const float* __restrict__ Wk, const float* __restrict__ bk,
    const float* __restrict__ Wv, const float* __restrict__ bv,
    const float* __restrict__ Ws, const float* __restrict__ bs,
    const float* __restrict__ Wg, const float* __restrict__ bg,
    float* __restrict__ q, float* __restrict__ kv,
    float* __restrict__ sk, float* __restrict__ g, int N)
{
    __shared__ float As[32][64];   // x tile, transposed: As[k][m]
    __shared__ float Bs[32][64];   // W tile: Bs[k][n]

    int bid = blockIdx.x;
    int mt  = bid / 5;
    int mat = bid % 5;
    const float* W; const float* b; float* o; int ldo;
    switch (mat) {
        case 0:  W = Wq; b = bq; o = q;       ldo = 64;  break;
        case 1:  W = Wk; b = bk; o = kv;      ldo = 128; break;
        case 2:  W = Wv; b = bv; o = kv + 64; ldo = 128; break;
        case 3:  W = Ws; b = bs; o = sk;      ldo = 64;  break;
        default: W = Wg; b = bg; o = g;       ldo = 64;  break;
    }

    int t = threadIdx.x;
    int m0 = mt * 64;
    int tx = t & 15, ty = t >> 4;
    int mload = t & 63;
    int kq0   = t >> 6;
    int row   = min(m0 + mload, N - 1);

    float acc[4][4] = {};

    for (int k0 = 0; k0 < K; k0 += 32) {
        #pragma unroll
        for (int i = 0; i < 2; ++i) {
            int kq = kq0 + 4 * i;
            float4 xv = *(const float4*)&x[(size_t)row * K + k0 + kq * 4];
            #pragma unroll
            for (int c = 0; c < 4; ++c) As[kq * 4 + c][mload] = ((const float*)&xv)[c];
        }
        #pragma unroll
        for (int i = 0; i < 2; ++i) {
            int kr = ty + 16 * i;
            *(float4*)&Bs[kr][tx * 4] = *(const float4*)&W[(size_t)(k0 + kr) * 64 + tx * 4];
        }
        __syncthreads();
        #pragma unroll
        for (int kk = 0; kk < 32; ++kk) {
            float4 a  = *(const float4*)&As[kk][ty * 4];
            float4 bb = *(const float4*)&Bs[kk][tx * 4];
            #pragma unroll
            for (int i = 0; i < 4; ++i)
                #pragma unroll
                for (int j = 0; j < 4; ++j)
                    acc[i][j] = fmaf(((const float*)&a)[i], ((const float*)&bb)[j], acc[i][j]);
        }
        __syncthreads();
    }

    float4 bias = *(const float4*)&b[tx * 4];
    #pragma unroll
    for (int i = 0; i < 4; ++i) {
        int m = m0 + ty * 4 + i;
        if (m < N) {
            float4 r;
            #pragma unroll
            for (int j = 0; j < 4; ++j) ((float*)&r)[j] = acc[i][j] + ((const float*)&bias)[j];
            *(float4*)&o[(size_t)m * ldo + tx * 4] = r;
        }
    }
}

// ============================ CSR edge pass v3 ============================
// Linearity refactor: alpha = scale*(q.k[s] + ef.g[d]);
//   out_pre = (sum ex*v[s] + (sum ex*ef) @ We) / sum ex
// Per edge: 1 ef row load + 2 kv gathers (prefetched, SGPR-based addressing),
// one fused lane-group reduction, exp, 3 accumulate FMAs. We-matvec once/node.
template<int C, int CHUNK>
__global__ __launch_bounds__(256) void edge_csr(
    const int* __restrict__ rowptr, const int* __restrict__ perm,
    const int* __restrict__ srcs, const float* __restrict__ ef,
    const float* __restrict__ We, const float* __restrict__ q,
    const float* __restrict__ g, const float* __restrict__ kv,
    const float* __restrict__ sk, float* __restrict__ out,
    float scale, int do_relu)
{
    __shared__ float Wel[32 * 64];
    __shared__ float exl[4][64];
    int t = threadIdx.x;
    for (int i = t; i < 32 * 64; i += 256) Wel[i] = We[i];
    __syncthreads();

    int lane  = t & 63;
    int wslot = t >> 6;
    int col   = lane & 31;
    int hsel  = (C == 64) ? 0 : (lane >> 5);

    int wid = blockIdx.x * 4 + wslot;
    int nw  = gridDim.x * 4;

    for (int d0 = wid; d0 < N_NODES; d0 += nw) {
        int d = __builtin_amdgcn_readfirstlane(d0);
        int r0 = rowptr[d], r1 = rowptr[d + 1];
        float qv = q[(size_t)d * 64 + lane];
        float gv = g[(size_t)d * 64 + lane];   // zero-padded for C==64, lane>=32
        float racc = 0.f, efacc = 0.f, rden = 0.f;

        for (int c0 = r0; c0 < r1; c0 += CHUNK) {
            int rem = min(CHUNK, r1 - c0);
            int e_l = (lane < rem) ? perm[c0 + lane] : 0;
            int s_l = (lane < rem) ? srcs[c0 + lane] : 0;

            int e_cur = __builtin_amdgcn_readlane(e_l, 0);
            int s_cur = __builtin_amdgcn_readlane(s_l, 0);
            float ef_n = ef[(size_t)e_cur * 32 + col];
            float kk_n = kv[(size_t)s_cur * 128 + lane];
            float vv_n = kv[(size_t)s_cur * 128 + 64 + lane];

            for (int i = 0; i < rem; ++i) {
                float efv = ef_n, kk = kk_n, vv = vv_n;
                if (i + 1 < rem) {             // prefetch next edge (SGPR saddr)
                    int e_nx = __builtin_amdgcn_readlane(e_l, i + 1);
                    int s_nx = __builtin_amdgcn_readlane(s_l, i + 1);
                    ef_n = ef[(size_t)e_nx * 32 + col];
                    kk_n = kv[(size_t)s_nx * 128 + lane];
                    vv_n = kv[(size_t)s_nx * 128 + 64 + lane];
                }
                float p = fmaf(qv, kk, efv * gv);
                #pragma unroll
                for (int off = C >> 1; off; off >>= 1) p += __shfl_xor(p, off, 64);
                float ex = __expf(p * scale);
                racc  = fmaf(vv,  ex, racc);
                efacc = fmaf(efv, ex, efacc);
                rden += ex;
            }
        }

        // finalize: (racc + efacc @ We) / rden + skip
        exl[wslot][lane] = efacc;              // same-wave LDS handoff
        float mv = 0.f;
        #pragma unroll 8
        for (int j = 0; j < 32; ++j)
            mv = fmaf(exl[wslot][hsel * 32 + j], Wel[j * 64 + lane], mv);
        float val = (racc + mv) / (rden + 1e-16f) + sk[(size_t)d * 64 + lane];
        if (do_relu) val = fmaxf(val, 0.f);
        out[(size_t)d * 64 + lane] = val;
    }
}

extern "C" void kernel_launch(void* const* d_in, const int* in_sizes, int n_in,
                              void* d_out, int out_size, void* d_ws, size_t ws_size,
                              hipStream_t stream) {
    const float* x   = (const float*)d_in[0];
    const int*   ei  = (const int*)d_in[1];
    const float* ef  = (const float*)d_in[2];
    const float* Wq1 = (const float*)d_in[3];  const float* bq1 = (const float*)d_in[4];
    const float* Wk1 = (const float*)d_in[5];  const float* bk1 = (const float*)d_in[6];
    const float* Wv1 = (const float*)d_in[7];  const float* bv1 = (const float*)d_in[8];
    const float* We1 = (const float*)d_in[9];
    const float* Ws1 = (const float*)d_in[10]; const float* bs1 = (const float*)d_in[11];
    const float* Wq2 = (const float*)d_in[12]; const float* bq2 = (const float*)d_in[13];
    const float* Wk2 = (const float*)d_in[14]; const float* bk2 = (const float*)d_in[15];
    const float* Wv2 = (const float*)d_in[16]; const float* bv2 = (const float*)d_in[17];
    const float* We2 = (const float*)d_in[18];
    const float* Ws2 = (const float*)d_in[19]; const float* bs2 = (const float*)d_in[20];
    float* out = (float*)d_out;

    const int N = N_NODES, E = N_EDGES;
    size_t NF = (size_t)N * 64;
    float* ws = (float*)d_ws;
    float* q     = ws;                      // N*64
    float* kv    = q + NF;                  // N*128 (k | v interleaved)
    float* sk    = kv + 2 * NF;             // N*64
    float* g     = sk + NF;                 // N*64
    float* Wg1   = g + NF;                  // 128*64
    float* bg1   = Wg1 + 128 * 64;          // 64
    float* Wg2   = bg1 + 64;                // 64*64
    float* bg2   = Wg2 + 64 * 64;           // 64
    int* cnt     = (int*)(bg2 + 64);        // N
    int* excl    = cnt + N;                 // N
    int* bsum    = excl + N;                // 128
    int* rowptr  = bsum + 128;              // N+1
    int* cursor  = rowptr + N + 1;          // N
    int* perm    = cursor + N;              // E
    int* srcs    = perm + E;                // E
    float* h1    = out;                     // layer-1 output aliases d_out (fully
                                            // rewritten by layer-2 epilogue)

    const int* src = ei;
    const int* dst = ei + E;

    dim3 b256(256);
    int gN    = (N + 255) / 256;
    int gN1   = (N + 1 + 255) / 256;
    int gE    = (E + 255) / 256;
    int gGemm = ((N + 63) / 64) * 5;        // node-tiles x 5 weight sets
    int gEdge = 2048;                       // 8192 persistent waves
    int nScanB = (N + 1023) / 1024;         // 98

    // ---------------- CSR build (shared by both layers) ----------------
    hipLaunchKernelGGL(zero_int, dim3(gN), b256, 0, stream, cnt, N);
    hipLaunchKernelGGL(hist_kernel, dim3(gE), b256, 0, stream, dst, cnt);
    hipLaunchKernelGGL(scan1, dim3(nScanB), b256, 0, stream, cnt, excl, bsum, N);
    hipLaunchKernelGGL(scan2, dim3(1), dim3(128), 0, stream, bsum, nScanB);
    hipLaunchKernelGGL(scan3, dim3(gN1), b256, 0, stream, excl, bsum, rowptr, cursor, N);
    hipLaunchKernelGGL(scatter_kernel, dim3(gE), b256, 0, stream, dst, src, cursor, perm, srcs);

    // ---------------- weight contractions ----------------
    hipLaunchKernelGGL((wg_build<128, 2>), dim3(1), b256, 0, stream, Wq1, bq1, We1, Wg1, bg1);
    hipLaunchKernelGGL((wg_build<64, 1>),  dim3(1), b256, 0, stream, Wq2, bq2, We2, Wg2, bg2);

    // ---------------- layer 1: H=2, C=32, K=128 ----------------
    hipLaunchKernelGGL((node_gemm<128>), dim3(gGemm), b256, 0, stream, x,
                       Wq1, bq1, Wk1, bk1, Wv1, bv1, Ws1, bs1, Wg1, bg1,
                       q, kv, sk, g, N);
    hipLaunchKernelGGL((edge_csr<32, 16>), dim3(gEdge), b256, 0, stream,
                       rowptr, perm, srcs, ef, We1, q, g, kv, sk, h1,
                       0.17677669529663687f, 1);

    // ---------------- layer 2: H=1, C=64, K=64 ----------------
    hipLaunchKernelGGL((node_gemm<64>), dim3(gGemm), b256, 0, stream, h1,
                       Wq2, bq2, Wk2, bk2, Wv2, bv2, Ws2, bs2, Wg2, bg2,
                       q, kv, sk, g, N);
    hipLaunchKernelGGL((edge_csr<64, 16>), dim3(gEdge), b256, 0, stream,
                       rowptr, perm, srcs, ef, We2, q, g, kv, sk, out,
                       0.125f, 0);
}

// Round 8
// 563.329 us; speedup vs baseline: 1.3247x; 1.0646x over previous
//
#include <hip/hip_runtime.h>
#include <cstdint>
#include <cstddef>

// Problem constants (from reference)
constexpr int N_NODES = 100000;
constexpr int N_EDGES = 1000000;

// ============================ CSR build ============================
__global__ void zero_int(int* __restrict__ p, int n) {
    int i = blockIdx.x * blockDim.x + threadIdx.x;
    if (i < n) p[i] = 0;
}

__global__ void hist_kernel(const int* __restrict__ dst, int* __restrict__ cnt) {
    int i = blockIdx.x * blockDim.x + threadIdx.x;
    if (i < N_EDGES) atomicAdd(&cnt[dst[i]], 1);
}

// per-block (1024 elems) exclusive scan + block sums
__global__ __launch_bounds__(256) void scan1(const int* __restrict__ cnt,
    int* __restrict__ excl, int* __restrict__ bsum, int n) {
    __shared__ int sh[256];
    int b = blockIdx.x, t = threadIdx.x;
    int base = b * 1024 + t * 4;
    int v0 = (base + 0 < n) ? cnt[base + 0] : 0;
    int v1 = (base + 1 < n) ? cnt[base + 1] : 0;
    int v2 = (base + 2 < n) ? cnt[base + 2] : 0;
    int v3 = (base + 3 < n) ? cnt[base + 3] : 0;
    int s = v0 + v1 + v2 + v3;
    sh[t] = s;
    __syncthreads();
    for (int off = 1; off < 256; off <<= 1) {
        int val = (t >= off) ? sh[t - off] : 0;
        __syncthreads();
        sh[t] += val;
        __syncthreads();
    }
    int prefix = sh[t] - s;
    if (t == 255) bsum[b] = sh[255];
    if (base + 0 < n) excl[base + 0] = prefix;
    if (base + 1 < n) excl[base + 1] = prefix + v0;
    if (base + 2 < n) excl[base + 2] = prefix + v0 + v1;
    if (base + 3 < n) excl[base + 3] = prefix + v0 + v1 + v2;
}

// single-block exclusive scan of block sums (nb <= 128)
__global__ __launch_bounds__(128) void scan2(int* __restrict__ bsum, int nb) {
    __shared__ int sh[128];
    int t = threadIdx.x;
    int v = (t < nb) ? bsum[t] : 0;
    sh[t] = v;
    __syncthreads();
    for (int off = 1; off < 128; off <<= 1) {
        int val = (t >= off) ? sh[t - off] : 0;
        __syncthreads();
        sh[t] += val;
        __syncthreads();
    }
    if (t < nb) bsum[t] = sh[t] - v;
}

__global__ void scan3(const int* __restrict__ excl, const int* __restrict__ bsum,
                      int* __restrict__ rowptr, int* __restrict__ cursor, int n) {
    int i = blockIdx.x * blockDim.x + threadIdx.x;
    if (i < n) { int r = excl[i] + bsum[i >> 10]; rowptr[i] = r; cursor[i] = r; }
    if (i == n) rowptr[n] = N_EDGES;
}

// scatter edge id AND its src node into dst-sorted order
__global__ void scatter_kernel(const int* __restrict__ dst, const int* __restrict__ src,
                               int* __restrict__ cursor,
                               int* __restrict__ perm, int* __restrict__ srcs) {
    int e = blockIdx.x * blockDim.x + threadIdx.x;
    if (e < N_EDGES) {
        int p = atomicAdd(&cursor[dst[e]], 1);
        perm[p] = e;
        srcs[p] = src[e];
    }
}

// ============================ Wg build ============================
// Wg[K,(h,j)] = sum_{c in head h} Wq[K,c]*We[j,c];  bg[(h,j)] = sum_c bq[c]*We[j,c]
// For H==1 only cols j<32 are nonzero (rest zero-padded so g is zero there).
template<int KDIM, int H>
__global__ __launch_bounds__(256) void wg_build(
    const float* __restrict__ Wq, const float* __restrict__ bq,
    const float* __restrict__ We,
    float* __restrict__ Wg, float* __restrict__ bg)
{
    __shared__ float wq[KDIM * 64];
    __shared__ float we[32 * 64];
    int t = threadIdx.x;
    for (int i = t; i < KDIM * 64; i += 256) wq[i] = Wq[i];
    for (int i = t; i < 32 * 64; i += 256) we[i] = We[i];
    __syncthreads();
    for (int idx = t; idx < KDIM * 64; idx += 256) {
        int K = idx >> 6, col = idx & 63;
        float s = 0.f;
        if (H == 2) {
            int h = col >> 5, j = col & 31;
            #pragma unroll 8
            for (int c = 0; c < 32; ++c)
                s = fmaf(wq[K * 64 + h * 32 + c], we[j * 64 + h * 32 + c], s);
        } else {
            int j = col;
            if (j < 32) {
                #pragma unroll 8
                for (int c = 0; c < 64; ++c)
                    s = fmaf(wq[K * 64 + c], we[j * 64 + c], s);
            }
        }
        Wg[idx] = s;
    }
    if (t < 64) {
        float s = 0.f;
        if (H == 2) {
            int h = t >> 5, j = t & 31;
            for (int c = 0; c < 32; ++c)
                s = fmaf(bq[h * 32 + c], we[j * 64 + h * 32 + c], s);
        } else {
            if (t < 32)
                for (int c = 0; c < 64; ++c)
                    s = fmaf(bq[c], we[t * 64 + c], s);
        }
        bg[t] = s;
    }
}

// ============================ node GEMM ============================
// o = x@W + b, FIVE weight sets selected by block (q, g, k, v, skip);
// q/g interleave into qg[N][128], k/v into kv[N][128].
// BM=128, BN=64, BK=32, 256 threads, 8x4 microtile.
template<int K>
__global__ __launch_bounds__(256) void node_gemm(
    const float* __restrict__ x,
    const float* __restrict__ Wq, const float* __restrict__ bq,
    const float* __restrict__ Wk, const float* __restrict__ bk,
    const float* __restrict__ Wv, const float* __restrict__ bv,
    const float* __restrict__ Ws, const float* __restrict__ bs,
    const float* __restrict__ Wg, const float* __restrict__ bg,
    float* __restrict__ qg, float* __restrict__ kv,
    float* __restrict__ sk, int N)
{
    __shared__ float As[32][128];  // x tile, transposed: As[k][m]
    __shared__ float Bs[32][64];   // W tile: Bs[k][n]

    int bid = blockIdx.x;
    int mt  = bid / 5;
    int mat = bid % 5;
    const float* W; const float* b; float* o; int ldo;
    switch (mat) {
        case 0:  W = Wq; b = bq; o = qg;      ldo = 128; break;
        case 1:  W = Wg; b = bg; o = qg + 64; ldo = 128; break;
        case 2:  W = Wk; b = bk; o = kv;      ldo = 128; break;
        case 3:  W = Wv; b = bv; o = kv + 64; ldo = 128; break;
        default: W = Ws; b = bs; o = sk;      ldo = 64;  break;
    }

    int t = threadIdx.x;
    int m0 = mt * 128;
    int tx = t & 15, ty = t >> 4;      // 16 col-groups x 16 row-groups(8 rows)
    int rl = t & 127;                  // load row within tile
    int kh = t >> 7;                   // 0/1
    int row = min(m0 + rl, N - 1);

    float acc[8][4] = {};

    for (int k0 = 0; k0 < K; k0 += 32) {
        #pragma unroll
        for (int i = 0; i < 4; ++i) {
            int kq = kh + 2 * i;       // 0..7
            float4 xv = *(const float4*)&x[(size_t)row * K + k0 + kq * 4];
            #pragma unroll
            for (int c = 0; c < 4; ++c) As[kq * 4 + c][rl] = ((const float*)&xv)[c];
        }
        #pragma unroll
        for (int i = 0; i < 2; ++i) {
            int kr = ty + 16 * i;
            *(float4*)&Bs[kr][tx * 4] = *(const float4*)&W[(size_t)(k0 + kr) * 64 + tx * 4];
        }
        __syncthreads();
        #pragma unroll
        for (int kk = 0; kk < 32; ++kk) {
            float4 a0 = *(const float4*)&As[kk][ty * 8];
            float4 a1 = *(const float4*)&As[kk][ty * 8 + 4];
            float4 bb = *(const float4*)&Bs[kk][tx * 4];
            #pragma unroll
            for (int i = 0; i < 4; ++i)
                #pragma unroll
                for (int j = 0; j < 4; ++j) {
                    acc[i][j]     = fmaf(((const float*)&a0)[i], ((const float*)&bb)[j], acc[i][j]);
                    acc[i + 4][j] = fmaf(((const float*)&a1)[i], ((const float*)&bb)[j], acc[i + 4][j]);
                }
        }
        __syncthreads();
    }

    float4 bias = *(const float4*)&b[tx * 4];
    #pragma unroll
    for (int i = 0; i < 8; ++i) {
        int m = m0 + ty * 8 + i;
        if (m < N) {
            float4 r;
            #pragma unroll
            for (int j = 0; j < 4; ++j) ((float*)&r)[j] = acc[i][j] + ((const float*)&bias)[j];
            *(float4*)&o[(size_t)m * ldo + tx * 4] = r;
        }
    }
}

// ============================ CSR edge pass v4 ============================
// alpha = scale*(q.k[s] + ef.g[d]);  out_pre = (Σ ex*v[s] + (Σ ex*ef)@We)/Σ ex
// Depth-2 software pipeline on (ef row, kv row) loads; nontemporal hints on
// single-use streams (ef/perm/srcs/qg/sk/out) so kv stays L3-resident.
template<int C, int CHUNK>
__global__ __launch_bounds__(256) void edge_csr(
    const int* __restrict__ rowptr, const int* __restrict__ perm,
    const int* __restrict__ srcs, const float* __restrict__ ef,
    const float* __restrict__ We, const float* __restrict__ qg,
    const float* __restrict__ kv, const float* __restrict__ sk,
    float* __restrict__ out, float scale, int do_relu)
{
    __shared__ float Wel[32 * 64];
    __shared__ float exl[4][64];
    int t = threadIdx.x;
    for (int i = t; i < 32 * 64; i += 256) Wel[i] = We[i];
    __syncthreads();

    int lane  = t & 63;
    int wslot = t >> 6;
    int col   = lane & 31;
    int hsel  = (C == 64) ? 0 : (lane >> 5);

    int wid = blockIdx.x * 4 + wslot;
    int nw  = gridDim.x * 4;

    for (int d0 = wid; d0 < N_NODES; d0 += nw) {
        int d = __builtin_amdgcn_readfirstlane(d0);
        int r0 = rowptr[d], r1 = rowptr[d + 1];
        float qv = __builtin_nontemporal_load(&qg[(size_t)d * 128 + lane]);
        float gv = __builtin_nontemporal_load(&qg[(size_t)d * 128 + 64 + lane]);
        float racc = 0.f, efacc = 0.f, rden = 0.f;

        for (int c0 = r0; c0 < r1; c0 += CHUNK) {
            int rem = min(CHUNK, r1 - c0);
            int e_l = (lane < rem) ? __builtin_nontemporal_load(&perm[c0 + lane]) : 0;
            int s_l = (lane < rem) ? __builtin_nontemporal_load(&srcs[c0 + lane]) : 0;

            // prologue: load edges 0 and 1 (clamped)
            int i1 = min(1, rem - 1);
            int eA = __builtin_amdgcn_readlane(e_l, 0);
            int sA = __builtin_amdgcn_readlane(s_l, 0);
            int eB = __builtin_amdgcn_readlane(e_l, i1);
            int sB = __builtin_amdgcn_readlane(s_l, i1);
            float efA = __builtin_nontemporal_load(&ef[(size_t)eA * 32 + col]);
            float kkA = kv[(size_t)sA * 128 + lane];
            float vvA = kv[(size_t)sA * 128 + 64 + lane];
            float efB = __builtin_nontemporal_load(&ef[(size_t)eB * 32 + col]);
            float kkB = kv[(size_t)sB * 128 + lane];
            float vvB = kv[(size_t)sB * 128 + 64 + lane];

            for (int i = 0; i < rem; i += 2) {
                // issue loads for edges i+2, i+3 (clamped; independent of consume)
                int iN0 = min(i + 2, rem - 1);
                int iN1 = min(i + 3, rem - 1);
                int eN0 = __builtin_amdgcn_readlane(e_l, iN0);
                int sN0 = __builtin_amdgcn_readlane(s_l, iN0);
                int eN1 = __builtin_amdgcn_readlane(e_l, iN1);
                int sN1 = __builtin_amdgcn_readlane(s_l, iN1);
                float efN0 = __builtin_nontemporal_load(&ef[(size_t)eN0 * 32 + col]);
                float kkN0 = kv[(size_t)sN0 * 128 + lane];
                float vvN0 = kv[(size_t)sN0 * 128 + 64 + lane];
                float efN1 = __builtin_nontemporal_load(&ef[(size_t)eN1 * 32 + col]);
                float kkN1 = kv[(size_t)sN1 * 128 + lane];
                float vvN1 = kv[(size_t)sN1 * 128 + 64 + lane];

                // consume edge i
                float p = fmaf(qv, kkA, efA * gv);
                #pragma unroll
                for (int off = C >> 1; off; off >>= 1) p += __shfl_xor(p, off, 64);
                float ex = __expf(p * scale);
                racc  = fmaf(vvA, ex, racc);
                efacc = fmaf(efA, ex, efacc);
                rden += ex;

                // consume edge i+1
                if (i + 1 < rem) {
                    float p2 = fmaf(qv, kkB, efB * gv);
                    #pragma unroll
                    for (int off = C >> 1; off; off >>= 1) p2 += __shfl_xor(p2, off, 64);
                    float ex2 = __expf(p2 * scale);
                    racc  = fmaf(vvB, ex2, racc);
                    efacc = fmaf(efB, ex2, efacc);
                    rden += ex2;
                }

                efA = efN0; kkA = kkN0; vvA = vvN0;
                efB = efN1; kkB = kkN1; vvB = vvN1;
            }
        }

        // finalize: (racc + efacc @ We) / rden + skip
        exl[wslot][lane] = efacc;              // same-wave LDS handoff
        float mv = 0.f;
        #pragma unroll 8
        for (int j = 0; j < 32; ++j)
            mv = fmaf(exl[wslot][hsel * 32 + j], Wel[j * 64 + lane], mv);
        float val = (racc + mv) / (rden + 1e-16f)
                  + __builtin_nontemporal_load(&sk[(size_t)d * 64 + lane]);
        if (do_relu) val = fmaxf(val, 0.f);
        __builtin_nontemporal_store(val, &out[(size_t)d * 64 + lane]);
    }
}

extern "C" void kernel_launch(void* const* d_in, const int* in_sizes, int n_in,
                              void* d_out, int out_size, void* d_ws, size_t ws_size,
                              hipStream_t stream) {
    const float* x   = (const float*)d_in[0];
    const int*   ei  = (const int*)d_in[1];
    const float* ef  = (const float*)d_in[2];
    const float* Wq1 = (const float*)d_in[3];  const float* bq1 = (const float*)d_in[4];
    const float* Wk1 = (const float*)d_in[5];  const float* bk1 = (const float*)d_in[6];
    const float* Wv1 = (const float*)d_in[7];  const float* bv1 = (const float*)d_in[8];
    const float* We1 = (const float*)d_in[9];
    const float* Ws1 = (const float*)d_in[10]; const float* bs1 = (const float*)d_in[11];
    const float* Wq2 = (const float*)d_in[12]; const float* bq2 = (const float*)d_in[13];
    const float* Wk2 = (const float*)d_in[14]; const float* bk2 = (const float*)d_in[15];
    const float* Wv2 = (const float*)d_in[16]; const float* bv2 = (const float*)d_in[17];
    const float* We2 = (const float*)d_in[18];
    const float* Ws2 = (const float*)d_in[19]; const float* bs2 = (const float*)d_in[20];
    float* out = (float*)d_out;

    const int N = N_NODES, E = N_EDGES;
    size_t NF = (size_t)N * 64;
    float* ws = (float*)d_ws;
    float* qg    = ws;                      // N*128 (q | g interleaved)
    float* kv    = qg + 2 * NF;             // N*128 (k | v interleaved)
    float* sk    = kv + 2 * NF;             // N*64
    float* Wg1   = sk + NF;                 // 128*64
    float* bg1   = Wg1 + 128 * 64;          // 64
    float* Wg2   = bg1 + 64;                // 64*64
    float* bg2   = Wg2 + 64 * 64;           // 64
    int* cnt     = (int*)(bg2 + 64);        // N
    int* excl    = cnt + N;                 // N
    int* bsum    = excl + N;                // 128
    int* rowptr  = bsum + 128;              // N+1
    int* cursor  = rowptr + N + 1;          // N
    int* perm    = cursor + N;              // E
    int* srcs    = perm + E;                // E
    float* h1    = out;                     // layer-1 output aliases d_out (fully
                                            // rewritten by layer-2 edge pass)

    const int* src = ei;
    const int* dst = ei + E;

    dim3 b256(256);
    int gN    = (N + 255) / 256;
    int gN1   = (N + 1 + 255) / 256;
    int gE    = (E + 255) / 256;
    int gGemm = ((N + 127) / 128) * 5;      // node-tiles x 5 weight sets
    int gEdge = 2048;                       // 8192 persistent waves
    int nScanB = (N + 1023) / 1024;         // 98

    // ---------------- CSR build (shared by both layers) ----------------
    hipLaunchKernelGGL(zero_int, dim3(gN), b256, 0, stream, cnt, N);
    hipLaunchKernelGGL(hist_kernel, dim3(gE), b256, 0, stream, dst, cnt);
    hipLaunchKernelGGL(scan1, dim3(nScanB), b256, 0, stream, cnt, excl, bsum, N);
    hipLaunchKernelGGL(scan2, dim3(1), dim3(128), 0, stream, bsum, nScanB);
    hipLaunchKernelGGL(scan3, dim3(gN1), b256, 0, stream, excl, bsum, rowptr, cursor, N);
    hipLaunchKernelGGL(scatter_kernel, dim3(gE), b256, 0, stream, dst, src, cursor, perm, srcs);

    // ---------------- weight contractions ----------------
    hipLaunchKernelGGL((wg_build<128, 2>), dim3(1), b256, 0, stream, Wq1, bq1, We1, Wg1, bg1);
    hipLaunchKernelGGL((wg_build<64, 1>),  dim3(1), b256, 0, stream, Wq2, bq2, We2, Wg2, bg2);

    // ---------------- layer 1: H=2, C=32, K=128 ----------------
    hipLaunchKernelGGL((node_gemm<128>), dim3(gGemm), b256, 0, stream, x,
                       Wq1, bq1, Wk1, bk1, Wv1, bv1, Ws1, bs1, Wg1, bg1,
                       qg, kv, sk, N);
    hipLaunchKernelGGL((edge_csr<32, 16>), dim3(gEdge), b256, 0, stream,
                       rowptr, perm, srcs, ef, We1, qg, kv, sk, h1,
                       0.17677669529663687f, 1);

    // ---------------- layer 2: H=1, C=64, K=64 ----------------
    hipLaunchKernelGGL((node_gemm<64>), dim3(gGemm), b256, 0, stream, h1,
                       Wq2, bq2, Wk2, bk2, Wv2, bv2, Ws2, bs2, Wg2, bg2,
                       qg, kv, sk, N);
    hipLaunchKernelGGL((edge_csr<64, 16>), dim3(gEdge), b256, 0, stream,
                       rowptr, perm, srcs, ef, We2, qg, kv, sk, out,
                       0.125f, 0);
}